// Round 6
// baseline (265.823 us; speedup 1.0000x reference)
//
#include <hip/hip_runtime.h>

#define IMG_H 2048
#define IMG_W 2048
#define NIMG 4

#define NBLK_INT (NIMG * (IMG_H / 2) * (IMG_W / 4) / 256)  // 8192 interior blocks
#define PER_IMG  (1024 + 2044)                             // 3068 border tiles per image
#define NBORDER  (NIMG * PER_IMG)                          // 12272 border tiles
#define NBLK_BOR ((NBORDER + 255) / 256)                   // 48 border blocks

__device__ __forceinline__ int refl(int i, int n) {
    i = (i < 0) ? -i : i;
    return (i >= n) ? (2 * n - 2 - i) : i;
}

__device__ __forceinline__ float clamp01(float v) {
    return fminf(fmaxf(v, 0.0f), 1.0f);
}

// 13-tap Malvar-He-Cutler demosaic at one pixel, phase (pr,pc) = (r&1, c&1).
// pr/pc are compile-time constants at all call sites -> dead cfas eliminated.
__device__ __forceinline__ void px_rgb(
    float x0,
    float xl, float xr, float xll, float xrr,      // row r: c-1, c+1, c-2, c+2
    float xu, float xd, float xuu, float xdd,      // col c: r-1, r+1, r-2, r+2
    float dul, float dur, float ddl, float ddr,    // diagonals
    int pr, int pc,
    float& R, float& G, float& B)
{
    float h1 = xl + xr, v1 = xu + xd;
    float h2 = xll + xrr, v2 = xuu + xdd;
    float diag = dul + dur + ddl + ddr;
    float cfa0 = 0.125f * (4.0f * x0 + 2.0f * (h1 + v1) - (h2 + v2));
    float cfa1 = 0.125f * (5.0f * x0 + 4.0f * h1 - h2 + 0.5f * v2 - diag);
    float cfa2 = 0.125f * (5.0f * x0 + 4.0f * v1 - v2 + 0.5f * h2 - diag);
    float cfa3 = 0.125f * (6.0f * x0 + 2.0f * diag - 1.5f * (h2 + v2));

    if (pr == 0) {
        if (pc == 0) { R = x0;   G = cfa0; B = cfa3; }
        else         { R = cfa1; G = x0;   B = cfa2; }
    } else {
        if (pc == 0) { R = cfa2; G = x0;   B = cfa1; }
        else         { R = cfa3; G = cfa0; B = x0;   }
    }
    R = clamp01(R); G = clamp01(G); B = clamp01(B);
}

// R6: shuffle-based halo exchange.
//  - Lanes in a wave cover contiguous 4-col groups, so the +-1/+-2 column
//    halo floats live in neighbor lanes' center loads. 8 side loads replaced
//    by 13 __shfl ops; only lanes 0/63 issue 4 small side loads (their halo
//    is in the adjacent wave). L1 traffic/wave: 14KB -> ~6.3KB; live VGPRs
//    for in-flight loads: 56 -> ~28 (better latency hiding via occupancy).
//  - Arithmetic bit-identical to R0 (same values, sourced cross-lane).
//  - Column-border lanes (c4==0/511) now participate in loads+shuffles
//    (neighbors need their data) and only skip the stores; row-border exits
//    are block-uniform so all 64 lanes are always active at the shuffles.
//  - Identity block map, R0 store order, single merged dispatch (R5: merge
//    is clock-adjusted neutral; swizzle/nt/store-reorder all regressed).
__global__ __launch_bounds__(256) void demosaic(
    const float* __restrict__ x, float* __restrict__ out)
{
    const size_t plane = (size_t)IMG_H * IMG_W;
    int bid = blockIdx.x;

    if (bid < NBLK_INT) {
        // ---------------- interior path ----------------
        int idx = bid * 256 + (int)threadIdx.x;

        int c4   = idx & 511;           // IMG_W/4 = 512 col groups
        int rest = idx >> 9;            // block-uniform
        int rp   = rest & 1023;         // IMG_H/2 = 1024 row pairs
        int n    = rest >> 10;
        if (rp == 0 || rp == 1023) return;   // block-uniform exit (full wave)
        int r = rp << 1;
        int c = c4 << 2;
        int lane = (int)threadIdx.x & 63;

        const float* p = x + (size_t)n * plane;
        const float* b = p + (size_t)r * IMG_W + c;

        // center loads: rows r-2 .. r+3, cols c..c+3
        float4 A  = *(const float4*)(b - 2 * IMG_W);
        float4 Bv = *(const float4*)(b - IMG_W);
        float4 C  = *(const float4*)(b);
        float4 D  = *(const float4*)(b + IMG_W);
        float4 E  = *(const float4*)(b + 2 * IMG_W);
        float4 F  = *(const float4*)(b + 3 * IMG_W);

        // wave-edge side loads (2 active lanes per instr). Addresses stay
        // inside the image for all interior row-pairs (r >= 2, r+2 <= 2046).
        bool le = (lane == 0), re = (lane == 63);
        float4 sB, sC, sD, sE;
        if (le || re) {
            const float* sb = b + (le ? -4 : 4);
            sB = *(const float4*)(sb - IMG_W);
            sC = *(const float4*)(sb);
            sD = *(const float4*)(sb + IMG_W);
            sE = *(const float4*)(sb + 2 * IMG_W);
        }

        // halo floats via cross-lane (bit-identical to loading them)
        float bm1 = __shfl_up(Bv.w, 1), bp4 = __shfl_down(Bv.x, 1);
        float cm2 = __shfl_up(C.z, 1),  cm1 = __shfl_up(C.w, 1);
        float cp4 = __shfl_down(C.x, 1), cp5 = __shfl_down(C.y, 1);
        float dm2 = __shfl_up(D.z, 1),  dm1 = __shfl_up(D.w, 1);
        float dp4 = __shfl_down(D.x, 1), dp5 = __shfl_down(D.y, 1);
        float em1 = __shfl_up(E.w, 1),  ep4 = __shfl_down(E.x, 1);
        if (le) { bm1 = sB.w; cm2 = sC.z; cm1 = sC.w; dm2 = sD.z; dm1 = sD.w; em1 = sE.w; }
        if (re) { bp4 = sB.x; cp4 = sC.x; cp5 = sC.y; dp4 = sD.x; dp5 = sD.y; ep4 = sE.x; }

        float wm2[4] = {A.x, A.y, A.z, A.w};                       // r-2: c..c+3
        float wm1[6] = {bm1, Bv.x, Bv.y, Bv.z, Bv.w, bp4};         // r-1: c-1..c+4
        float w0[8]  = {cm2, cm1, C.x, C.y, C.z, C.w, cp4, cp5};   // r:   c-2..c+5
        float w1[8]  = {dm2, dm1, D.x, D.y, D.z, D.w, dp4, dp5};   // r+1: c-2..c+5
        float w2[6]  = {em1, E.x, E.y, E.z, E.w, ep4};             // r+2: c-1..c+4
        float w3[4]  = {F.x, F.y, F.z, F.w};                       // r+3: c..c+3

        float R0[4], G0[4], B0[4], R1[4], G1[4], B1[4];
        #pragma unroll
        for (int j = 0; j < 4; j++) {
            // pixel (r, c+j): pr=0
            px_rgb(w0[j + 2],
                   w0[j + 1], w0[j + 3], w0[j], w0[j + 4],
                   wm1[j + 1], w1[j + 2], wm2[j], w2[j + 1],
                   wm1[j], wm1[j + 2], w1[j + 1], w1[j + 3],
                   0, j & 1, R0[j], G0[j], B0[j]);
            // pixel (r+1, c+j): pr=1
            px_rgb(w1[j + 2],
                   w1[j + 1], w1[j + 3], w1[j], w1[j + 4],
                   w0[j + 2], w2[j + 1], wm1[j + 1], w3[j],
                   w0[j + 1], w0[j + 3], w2[j], w2[j + 2],
                   1, j & 1, R1[j], G1[j], B1[j]);
        }

        // column-border tiles are produced by the border path; these lanes
        // only existed to feed the shuffles above.
        if (c4 != 0 && c4 != 511) {
            size_t ob = (size_t)n * 3 * plane + (size_t)r * IMG_W + c;
            // store order exactly as R0 baseline (best measured: 261.1us)
            *(float4*)(out + ob)                     = make_float4(R0[0], R0[1], R0[2], R0[3]);
            *(float4*)(out + ob + plane)             = make_float4(G0[0], G0[1], G0[2], G0[3]);
            *(float4*)(out + ob + 2 * plane)         = make_float4(B0[0], B0[1], B0[2], B0[3]);
            *(float4*)(out + ob + IMG_W)             = make_float4(R1[0], R1[1], R1[2], R1[3]);
            *(float4*)(out + ob + IMG_W + plane)     = make_float4(G1[0], G1[1], G1[2], G1[3]);
            *(float4*)(out + ob + IMG_W + 2 * plane) = make_float4(B1[0], B1[1], B1[2], B1[3]);
        }
    } else {
        // ---------------- border path (block-uniform branch) ----------------
        int idx = (bid - NBLK_INT) * 256 + (int)threadIdx.x;
        if (idx >= NBORDER) return;
        int n = idx / PER_IMG;
        int t = idx - n * PER_IMG;
        int rp, c4;
        if (t < 1024) { rp = (t >> 9) * 1023; c4 = t & 511; }
        else          { int j = t - 1024; rp = 1 + (j >> 1); c4 = (j & 1) * 511; }
        int r = rp << 1;
        int c = c4 << 2;

        const float* p = x + (size_t)n * IMG_H * IMG_W;
        size_t ob = (size_t)n * 3 * plane + (size_t)r * IMG_W + c;

        // unroll 1: keep this path register-light so it cannot degrade the
        // interior path's occupancy (one shared allocation per kernel).
        #pragma unroll 1
        for (int i = 0; i < 2; i++) {
            int rr = r + i;                        // r even -> pr == i
            int rm1 = refl(rr - 1, IMG_H), rm2 = refl(rr - 2, IMG_H);
            int rp1 = refl(rr + 1, IMG_H), rp2 = refl(rr + 2, IMG_H);
            const float* p0r  = p + (size_t)rr  * IMG_W;
            const float* pm1r = p + (size_t)rm1 * IMG_W;
            const float* pm2r = p + (size_t)rm2 * IMG_W;
            const float* pp1r = p + (size_t)rp1 * IMG_W;
            const float* pp2r = p + (size_t)rp2 * IMG_W;
            #pragma unroll 1
            for (int j = 0; j < 4; j++) {
                int cc  = c + j;
                int cm1 = refl(cc - 1, IMG_W), cm2 = refl(cc - 2, IMG_W);
                int cp1 = refl(cc + 1, IMG_W), cp2 = refl(cc + 2, IMG_W);
                float R, G, B;
                if (i == 0)
                    px_rgb(p0r[cc],
                           p0r[cm1], p0r[cp1], p0r[cm2], p0r[cp2],
                           pm1r[cc], pp1r[cc], pm2r[cc], pp2r[cc],
                           pm1r[cm1], pm1r[cp1], pp1r[cm1], pp1r[cp1],
                           0, cc & 1, R, G, B);
                else
                    px_rgb(p0r[cc],
                           p0r[cm1], p0r[cp1], p0r[cm2], p0r[cp2],
                           pm1r[cc], pp1r[cc], pm2r[cc], pp2r[cc],
                           pm1r[cm1], pm1r[cp1], pp1r[cm1], pp1r[cp1],
                           1, cc & 1, R, G, B);
                size_t o = ob + (size_t)i * IMG_W + j;
                out[o]             = R;
                out[o + plane]     = G;
                out[o + 2 * plane] = B;
            }
        }
    }
}

extern "C" void kernel_launch(void* const* d_in, const int* in_sizes, int n_in,
                              void* d_out, int out_size, void* d_ws, size_t ws_size,
                              hipStream_t stream) {
    const float* x = (const float*)d_in[0];
    float* out = (float*)d_out;

    // Single dispatch: 8192 interior blocks + 48 border blocks, fully overlapped.
    demosaic<<<dim3(NBLK_INT + NBLK_BOR), dim3(256), 0, stream>>>(x, out);
}

// Round 7
// 262.989 us; speedup vs baseline: 1.0108x; 1.0108x over previous
//
#include <hip/hip_runtime.h>

#define IMG_H 2048
#define IMG_W 2048
#define NIMG 4

__device__ __forceinline__ int refl(int i, int n) {
    i = (i < 0) ? -i : i;
    return (i >= n) ? (2 * n - 2 - i) : i;
}

__device__ __forceinline__ float clamp01(float v) {
    return fminf(fmaxf(v, 0.0f), 1.0f);
}

// 13-tap Malvar-He-Cutler demosaic at one pixel, phase (pr,pc) = (r&1, c&1).
// pr/pc are compile-time constants at all call sites -> dead cfas eliminated.
__device__ __forceinline__ void px_rgb(
    float x0,
    float xl, float xr, float xll, float xrr,      // row r: c-1, c+1, c-2, c+2
    float xu, float xd, float xuu, float xdd,      // col c: r-1, r+1, r-2, r+2
    float dul, float dur, float ddl, float ddr,    // diagonals
    int pr, int pc,
    float& R, float& G, float& B)
{
    float h1 = xl + xr, v1 = xu + xd;
    float h2 = xll + xrr, v2 = xuu + xdd;
    float diag = dul + dur + ddl + ddr;
    float cfa0 = 0.125f * (4.0f * x0 + 2.0f * (h1 + v1) - (h2 + v2));
    float cfa1 = 0.125f * (5.0f * x0 + 4.0f * h1 - h2 + 0.5f * v2 - diag);
    float cfa2 = 0.125f * (5.0f * x0 + 4.0f * v1 - v2 + 0.5f * h2 - diag);
    float cfa3 = 0.125f * (6.0f * x0 + 2.0f * diag - 1.5f * (h2 + v2));

    if (pr == 0) {
        if (pc == 0) { R = x0;   G = cfa0; B = cfa3; }
        else         { R = cfa1; G = x0;   B = cfa2; }
    } else {
        if (pc == 0) { R = cfa2; G = x0;   B = cfa1; }
        else         { R = cfa3; G = cfa0; B = x0;   }
    }
    R = clamp01(R); G = clamp01(G); B = clamp01(B);
}

// R7: exact revert to the best-measured configuration (R0, 261.1us).
// Session ledger: XCD swizzle -6..-9us (broke write-stream DRAM locality);
// nt stores ~0..-4; plane-grouped stores <=0; border merge ~0; shuffle-halo
// ~0. The interior kernel is insensitive to read locality, VMEM count,
// occupancy, and write policy -- it is at its mixed-stream memory floor.
// R0's two-dispatch, identity-map, interleaved-store config is the only one
// measured at 261us; restore it verbatim.
__global__ __launch_bounds__(256) void demosaic_interior(
    const float* __restrict__ x, float* __restrict__ out)
{
    int idx = blockIdx.x * blockDim.x + threadIdx.x;
    int c4   = idx & 511;           // IMG_W/4 = 512 col groups
    int rest = idx >> 9;
    int rp   = rest & 1023;         // IMG_H/2 = 1024 row pairs
    int n    = rest >> 10;
    if (rp == 0 || rp == 1023 || c4 == 0 || c4 == 511) return;  // border tiles
    int r = rp << 1;
    int c = c4 << 2;

    const float* p = x + (size_t)n * IMG_H * IMG_W;
    const size_t plane = (size_t)IMG_H * IMG_W;
    size_t ob = (size_t)n * 3 * plane + (size_t)r * IMG_W + c;

    const float* b = p + (size_t)r * IMG_W + c;
    float4 m2  = *(const float4*)(b - 2 * IMG_W);
    float4 m1l = *(const float4*)(b - IMG_W - 4);
    float4 m1c = *(const float4*)(b - IMG_W);
    float4 m1r = *(const float4*)(b - IMG_W + 4);
    float4 z0l = *(const float4*)(b - 4);
    float4 z0c = *(const float4*)(b);
    float4 z0r = *(const float4*)(b + 4);
    float4 z1l = *(const float4*)(b + IMG_W - 4);
    float4 z1c = *(const float4*)(b + IMG_W);
    float4 z1r = *(const float4*)(b + IMG_W + 4);
    float4 z2l = *(const float4*)(b + 2 * IMG_W - 4);
    float4 z2c = *(const float4*)(b + 2 * IMG_W);
    float4 z2r = *(const float4*)(b + 2 * IMG_W + 4);
    float4 p3  = *(const float4*)(b + 3 * IMG_W);

    float wm2[4] = {m2.x, m2.y, m2.z, m2.w};                                 // r-2: c..c+3
    float wm1[6] = {m1l.w, m1c.x, m1c.y, m1c.z, m1c.w, m1r.x};               // r-1: c-1..c+4
    float w0[8]  = {z0l.z, z0l.w, z0c.x, z0c.y, z0c.z, z0c.w, z0r.x, z0r.y}; // r:   c-2..c+5
    float w1[8]  = {z1l.z, z1l.w, z1c.x, z1c.y, z1c.z, z1c.w, z1r.x, z1r.y}; // r+1: c-2..c+5
    float w2[6]  = {z2l.w, z2c.x, z2c.y, z2c.z, z2c.w, z2r.x};               // r+2: c-1..c+4
    float w3[4]  = {p3.x, p3.y, p3.z, p3.w};                                 // r+3: c..c+3

    float R0[4], G0[4], B0[4], R1[4], G1[4], B1[4];
    #pragma unroll
    for (int j = 0; j < 4; j++) {
        // pixel (r, c+j): pr=0
        px_rgb(w0[j + 2],
               w0[j + 1], w0[j + 3], w0[j], w0[j + 4],
               wm1[j + 1], w1[j + 2], wm2[j], w2[j + 1],
               wm1[j], wm1[j + 2], w1[j + 1], w1[j + 3],
               0, j & 1, R0[j], G0[j], B0[j]);
        // pixel (r+1, c+j): pr=1
        px_rgb(w1[j + 2],
               w1[j + 1], w1[j + 3], w1[j], w1[j + 4],
               w0[j + 2], w2[j + 1], wm1[j + 1], w3[j],
               w0[j + 1], w0[j + 3], w2[j], w2[j + 2],
               1, j & 1, R1[j], G1[j], B1[j]);
    }

    *(float4*)(out + ob)                     = make_float4(R0[0], R0[1], R0[2], R0[3]);
    *(float4*)(out + ob + plane)             = make_float4(G0[0], G0[1], G0[2], G0[3]);
    *(float4*)(out + ob + 2 * plane)         = make_float4(B0[0], B0[1], B0[2], B0[3]);
    *(float4*)(out + ob + IMG_W)             = make_float4(R1[0], R1[1], R1[2], R1[3]);
    *(float4*)(out + ob + IMG_W + plane)     = make_float4(G1[0], G1[1], G1[2], G1[3]);
    *(float4*)(out + ob + IMG_W + 2 * plane) = make_float4(B1[0], B1[1], B1[2], B1[3]);
}

// Border kernel: covers row-pairs {0,1023} (all columns) and col-groups
// {0,511} (remaining row-pairs). 3068 tiles/image, 12272 threads total.
__global__ __launch_bounds__(256) void demosaic_border(
    const float* __restrict__ x, float* __restrict__ out)
{
    const int PER_IMG = 1024 + 2044;  // 3068 border tiles per image
    int idx = blockIdx.x * blockDim.x + threadIdx.x;
    if (idx >= NIMG * PER_IMG) return;
    int n = idx / PER_IMG;
    int t = idx - n * PER_IMG;
    int rp, c4;
    if (t < 1024) { rp = (t >> 9) * 1023; c4 = t & 511; }
    else          { int j = t - 1024; rp = 1 + (j >> 1); c4 = (j & 1) * 511; }
    int r = rp << 1;
    int c = c4 << 2;

    const float* p = x + (size_t)n * IMG_H * IMG_W;
    const size_t plane = (size_t)IMG_H * IMG_W;
    size_t ob = (size_t)n * 3 * plane + (size_t)r * IMG_W + c;

    #pragma unroll
    for (int i = 0; i < 2; i++) {
        int rr = r + i;                        // r even -> pr == i
        int rm1 = refl(rr - 1, IMG_H), rm2 = refl(rr - 2, IMG_H);
        int rp1 = refl(rr + 1, IMG_H), rp2 = refl(rr + 2, IMG_H);
        const float* p0r  = p + (size_t)rr  * IMG_W;
        const float* pm1r = p + (size_t)rm1 * IMG_W;
        const float* pm2r = p + (size_t)rm2 * IMG_W;
        const float* pp1r = p + (size_t)rp1 * IMG_W;
        const float* pp2r = p + (size_t)rp2 * IMG_W;
        #pragma unroll
        for (int j = 0; j < 4; j++) {
            int cc  = c + j;
            int cm1 = refl(cc - 1, IMG_W), cm2 = refl(cc - 2, IMG_W);
            int cp1 = refl(cc + 1, IMG_W), cp2 = refl(cc + 2, IMG_W);
            float R, G, B;
            px_rgb(p0r[cc],
                   p0r[cm1], p0r[cp1], p0r[cm2], p0r[cp2],
                   pm1r[cc], pp1r[cc], pm2r[cc], pp2r[cc],
                   pm1r[cm1], pm1r[cp1], pp1r[cm1], pp1r[cp1],
                   i, cc & 1, R, G, B);
            size_t o = ob + (size_t)i * IMG_W + j;
            out[o]             = R;
            out[o + plane]     = G;
            out[o + 2 * plane] = B;
        }
    }
}

extern "C" void kernel_launch(void* const* d_in, const int* in_sizes, int n_in,
                              void* d_out, int out_size, void* d_ws, size_t ws_size,
                              hipStream_t stream) {
    const float* x = (const float*)d_in[0];
    float* out = (float*)d_out;

    // Interior: full pow2 grid, edge tiles early-return.
    const int total = NIMG * (IMG_H / 2) * (IMG_W / 4);  // 2,097,152
    demosaic_interior<<<dim3(total / 256), dim3(256), 0, stream>>>(x, out);

    // Border: 4 * 3068 = 12,272 threads.
    const int btotal = NIMG * (1024 + 2044);
    demosaic_border<<<dim3((btotal + 255) / 256), dim3(256), 0, stream>>>(x, out);
}